// Round 1
// 535.941 us; speedup vs baseline: 1.0605x; 1.0605x over previous
//
#include <hip/hip_runtime.h>
#include <hip/hip_bf16.h>

#define B_   32
#define T_   2048
#define DIN  1024
#define DHID 2048
#define TAG  2

// ---- 8-phase 256x256x64 GEMM geometry ----
#define BM   256
#define BN   256
#define BK   64
#define NT   (DIN / BK)          // 16 K-tiles

typedef __attribute__((ext_vector_type(8))) short bf16x8;   // 8 bf16 = 4 VGPRs
typedef __attribute__((ext_vector_type(4))) float f32x4;
typedef __attribute__((ext_vector_type(4))) int   i32x4;

union BF8 { bf16x8 v; i32x4 i; unsigned int u[4]; };

// fp32 -> bf16 round-to-nearest-even, pure integer ops
__device__ inline unsigned int f2bf_u(float f) {
    unsigned int u = __float_as_uint(f);
    return (u + 0x7FFFu + ((u >> 16) & 1u)) >> 16;
}
__device__ inline unsigned int pack2bf(float a, float b) {
    return f2bf_u(a) | (f2bf_u(b) << 16);
}

#define BARRIER()  asm volatile("s_barrier" ::: "memory")
#define LGKM0()    asm volatile("s_waitcnt lgkmcnt(0)" ::: "memory")
#define VMCNT(n)   asm volatile("s_waitcnt vmcnt(" #n ")" ::: "memory")

// ---- W1 fp32 [DHID][DIN] -> bf16 same layout; also zero pooled ----
__global__ void convert_w1(const float* __restrict__ W1,
                           unsigned short* __restrict__ W1b,
                           float* __restrict__ pooled) {
    int idx = blockIdx.x * blockDim.x + threadIdx.x;   // one float4 per thread
    float4 f = ((const float4*)W1)[idx];
    ((uint2*)W1b)[idx] = uint2{pack2bf(f.x, f.y), pack2bf(f.z, f.w)};
    if (idx < B_ * DHID / 4) ((float4*)pooled)[idx] = float4{0.f, 0.f, 0.f, 0.f};
}

// ---- h fp32 [B,T,DIN] -> bf16. Masked rows (t >= len) are SKIPPED entirely:
// the GEMM epilogue masks rows >= len, so stale/garbage bf16 there is harmless.
__global__ void convert_h(const float* __restrict__ h,
                          const int*   __restrict__ text_len,
                          unsigned short* __restrict__ hb) {
    const int b   = blockIdx.y;
    const int idx = blockIdx.x * 256 + threadIdx.x;       // 0 .. T_*DIN/8-1
    const int t   = idx >> 7;                             // DIN/8 = 128 thr/row
    if (t >= text_len[b]) return;                         // wave-uniform (128 thr/row)
    const size_t gi = (size_t)b * (T_ * DIN / 8) + idx;   // uint4 index
    float4 f0 = ((const float4*)h)[gi * 2];
    float4 f1 = ((const float4*)h)[gi * 2 + 1];
    uint4 o;
    o.x = pack2bf(f0.x, f0.y);
    o.y = pack2bf(f0.z, f0.w);
    o.z = pack2bf(f1.x, f1.y);
    o.w = pack2bf(f1.z, f1.w);
    ((uint4*)hb)[gi] = o;
}

// ---- main GEMM: 256x256 tile, 8 waves (2M x 4N), BK=64, dbuf LDS (128 KB),
// 4 phases/K-tile with counted vmcnt(6) (T3+T4) + setprio (T5) + XOR swizzle (T2).
//
// LDS slots per buffer d in {0,1}: A[d] rows 0..255, B[d] rows 0..255; within a
// row, 16B chunk c stored at slot c ^ (row&7)  (conflict-free ds_read_b128).
//
// Schedule invariants (race analysis):
//   slot        last ds_read      overwritten by issue at       separation
//   A-half0(t)  phase 0 of t      phase 1 of t   (-> t+2)       ph0 lgkm0+bar
//   B-half0(t)  phase 0 of t      phase 2 of t   (-> t+2)       2 barriers
//   B-half1(t)  phase 1 of t      phase 3 of t   (-> t+2)       2 barriers
//   A-half1(t)  phase 2 of t      phase 0 of t+1 (-> t+2)       2 barriers
// vmcnt(6) once per K-tile (end of phase 3) leaves exactly the 3 newest
// half-tiles (A0,B0,B1 of t+2) in flight and guarantees K-tile t+1 landed.
__global__ __launch_bounds__(512, 2) void scorer_gemm_8ph(
    const unsigned short* __restrict__ hb,    // [B,T,DIN] bf16
    const int*            __restrict__ text_len,
    const unsigned short* __restrict__ W1b,   // [DHID,DIN] bf16
    const float*          __restrict__ b1,
    float*                __restrict__ pooled) {

    const int nt  = blockIdx.x;               // n fastest -> A-panel L2 reuse
    const int tt  = blockIdx.y;
    const int b   = blockIdx.z;
    const int len = text_len[b];
    const int t0  = tt * BM;
    if (t0 >= len) return;                    // fully masked tile (block-uniform)
    const int n0  = nt * BN;

    __shared__ __align__(16) unsigned short lds[4 * BM * BK];  // 128 KB: A0 A1 B0 B1

    const int tid  = threadIdx.x;
    const int lane = tid & 63;
    const int wid  = tid >> 6;       // 0..7
    const int wm   = wid >> 2;       // 0..1  (M wave)
    const int wn   = wid & 3;        // 0..3  (N wave)
    const int quad = lane >> 4;
    const int l15  = lane & 15;

    // staging: per global_load_lds issue, 512 threads cover 64 rows (8 rows/wave,
    // 8 x 16B chunks/row). LDS dest is wave-uniform; HW adds lane*16.
    const int srow   = lane >> 3;                 // 0..7 row within wave's 8-row group
    const int schunk = (lane & 7) ^ srow;         // pre-swizzled source chunk
    const unsigned short* gA = hb  + ((size_t)b * T_ + t0 + wid * 8 + srow) * DIN + schunk * 8;
    const unsigned short* gB = W1b + ((size_t)(n0 + wid * 8 + srow)) * DIN + schunk * 8;
    const int sdst = wid * 512;                   // shorts, wave-uniform

    auto stageA = [&](int d, int h, int k0) {
#pragma unroll
        for (int i = 0; i < 2; ++i) {
            const unsigned short* gp = gA + (size_t)(h * 128 + i * 64) * DIN + k0;
            __builtin_amdgcn_global_load_lds(
                (const __attribute__((address_space(1))) void*)gp,
                (__attribute__((address_space(3))) void*)(lds + d * 16384 + (h * 128 + i * 64) * 64 + sdst),
                16, 0, 0);
        }
    };
    auto stageB = [&](int d, int h, int k0) {
#pragma unroll
        for (int i = 0; i < 2; ++i) {
            const unsigned short* gp = gB + (size_t)(h * 128 + i * 64) * DIN + k0;
            __builtin_amdgcn_global_load_lds(
                (const __attribute__((address_space(1))) void*)gp,
                (__attribute__((address_space(3))) void*)(lds + 32768 + d * 16384 + (h * 128 + i * 64) * 64 + sdst),
                16, 0, 0);
        }
    };

    // fragment rows: mi 0..7 -> row (mi>>2)*128 + wm*64 + (mi&3)*16  (mi<4 = half0)
    //                ni 0..3 -> row (ni>>1)*128 + wn*32 + (ni&1)*16  (ni<2 = half0)
    auto rdA = [&](const unsigned short* As, int mi, int ks) -> i32x4 {
        int row  = (mi >> 2) * 128 + wm * 64 + (mi & 3) * 16 + l15;
        int slot = (ks * 4 + quad) ^ (l15 & 7);
        return *(const i32x4*)(As + row * 64 + slot * 8);
    };
    auto rdB = [&](const unsigned short* Bs, int ni, int ks) -> i32x4 {
        int row  = (ni >> 1) * 128 + wn * 32 + (ni & 1) * 16 + l15;
        int slot = (ks * 4 + quad) ^ (l15 & 7);
        return *(const i32x4*)(Bs + row * 64 + slot * 8);
    };

    f32x4 acc[8][4] = {};
    BF8 a[4][2], bb[4][2];

    // ---- prologue: K-tile 0 complete + 3 half-tiles of K-tile 1 in flight ----
    stageA(0, 0, 0);  stageB(0, 0, 0);  stageB(0, 1, 0);  stageA(0, 1, 0);
    stageA(1, 0, BK); stageB(1, 0, BK); stageB(1, 1, BK);
    VMCNT(6);                      // oldest 8 loads (= all of K-tile 0) landed
    BARRIER();

    for (int t = 0; t < NT; ++t) {
        const int k0 = t * BK;
        const unsigned short* As = lds + (t & 1) * 16384;
        const unsigned short* Bs = lds + 32768 + (t & 1) * 16384;

        // ---- phase 0: read A-half0 (mi0-3) + B-half0 (ni0-1); stage A-half1(t+1)
#pragma unroll
        for (int mi = 0; mi < 4; ++mi)
#pragma unroll
            for (int ks = 0; ks < 2; ++ks)
                a[mi][ks].i = rdA(As, mi, ks);
#pragma unroll
        for (int ni = 0; ni < 2; ++ni)
#pragma unroll
            for (int ks = 0; ks < 2; ++ks)
                bb[ni][ks].i = rdB(Bs, ni, ks);
        if (t + 1 < NT) stageA((t + 1) & 1, 1, k0 + BK);
        BARRIER();
        LGKM0();
        __builtin_amdgcn_s_setprio(1);
#pragma unroll
        for (int mi = 0; mi < 4; ++mi)
#pragma unroll
            for (int ni = 0; ni < 2; ++ni)
#pragma unroll
                for (int ks = 0; ks < 2; ++ks)
                    acc[mi][ni] = __builtin_amdgcn_mfma_f32_16x16x32_bf16(
                        a[mi][ks].v, bb[ni][ks].v, acc[mi][ni], 0, 0, 0);
        __builtin_amdgcn_s_setprio(0);
        BARRIER();

        // ---- phase 1: read B-half1 (ni2-3); stage A-half0(t+2)
#pragma unroll
        for (int ni = 2; ni < 4; ++ni)
#pragma unroll
            for (int ks = 0; ks < 2; ++ks)
                bb[ni][ks].i = rdB(Bs, ni, ks);
        if (t + 2 < NT) stageA(t & 1, 0, k0 + 2 * BK);
        BARRIER();
        LGKM0();
        __builtin_amdgcn_s_setprio(1);
#pragma unroll
        for (int mi = 0; mi < 4; ++mi)
#pragma unroll
            for (int ni = 2; ni < 4; ++ni)
#pragma unroll
                for (int ks = 0; ks < 2; ++ks)
                    acc[mi][ni] = __builtin_amdgcn_mfma_f32_16x16x32_bf16(
                        a[mi][ks].v, bb[ni][ks].v, acc[mi][ni], 0, 0, 0);
        __builtin_amdgcn_s_setprio(0);
        BARRIER();

        // ---- phase 2: read A-half1 (mi4-7, reusing a[]); stage B-half0(t+2)
#pragma unroll
        for (int mi = 0; mi < 4; ++mi)
#pragma unroll
            for (int ks = 0; ks < 2; ++ks)
                a[mi][ks].i = rdA(As, mi + 4, ks);
        if (t + 2 < NT) stageB(t & 1, 0, k0 + 2 * BK);
        BARRIER();
        LGKM0();
        __builtin_amdgcn_s_setprio(1);
#pragma unroll
        for (int mi = 0; mi < 4; ++mi)
#pragma unroll
            for (int ni = 2; ni < 4; ++ni)
#pragma unroll
                for (int ks = 0; ks < 2; ++ks)
                    acc[4 + mi][ni] = __builtin_amdgcn_mfma_f32_16x16x32_bf16(
                        a[mi][ks].v, bb[ni][ks].v, acc[4 + mi][ni], 0, 0, 0);
        __builtin_amdgcn_s_setprio(0);
        BARRIER();

        // ---- phase 3: no ds_read (bb[0..1] retained); stage B-half1(t+2); vmcnt
        if (t + 2 < NT) stageB(t & 1, 1, k0 + 2 * BK);
        if (t < NT - 2)       { VMCNT(6); }   // steady: 3 half-tiles stay in flight
        else if (t == NT - 2) { VMCNT(0); }   // tail: drain last prefetch
        BARRIER();
        __builtin_amdgcn_s_setprio(1);
#pragma unroll
        for (int mi = 0; mi < 4; ++mi)
#pragma unroll
            for (int ni = 0; ni < 2; ++ni)
#pragma unroll
                for (int ks = 0; ks < 2; ++ks)
                    acc[4 + mi][ni] = __builtin_amdgcn_mfma_f32_16x16x32_bf16(
                        a[mi][ks].v, bb[ni][ks].v, acc[4 + mi][ni], 0, 0, 0);
        __builtin_amdgcn_s_setprio(0);
        BARRIER();
    }

    // ---- epilogue: +b1, relu, mask, reduce over m (regs then quad-shfl), atomicAdd
    // C/D layout: col = lane&15 (n), row = quad*4 + reg (m)
#pragma unroll
    for (int ni = 0; ni < 4; ++ni) {
        int n = n0 + (ni >> 1) * 128 + wn * 32 + (ni & 1) * 16 + l15;
        float bias = b1[n];
        float colsum = 0.f;
#pragma unroll
        for (int mi = 0; mi < 8; ++mi) {
            int trow = t0 + (mi >> 2) * 128 + wm * 64 + (mi & 3) * 16 + quad * 4;
#pragma unroll
            for (int r = 0; r < 4; ++r) {
                float v = acc[mi][ni][r] + bias;
                v = v > 0.f ? v : 0.f;
                if (trow + r < len) colsum += v;
            }
        }
        colsum += __shfl_xor(colsum, 16);
        colsum += __shfl_xor(colsum, 32);
        if (quad == 0) atomicAdd(&pooled[b * DHID + n], colsum);
    }
}

// ---- fallback (no hb workspace) ----
__global__ void scorer_gemm_direct(const float* __restrict__ hin,
                                   const int*   __restrict__ text_len,
                                   const unsigned short* __restrict__ W1b,
                                   const float* __restrict__ b1,
                                   float*       __restrict__ pooled) {
    const int tt  = blockIdx.x;
    const int b   = blockIdx.y;
    const int len = text_len[b];
    const int t0  = tt * 64;
    if (t0 >= len) return;
    const int tid = threadIdx.x, lane = tid & 63, wid = tid >> 6;
    const int wrow = wid >> 1, wcol = wid & 1, quad = lane >> 4, l15 = lane & 15;
    const float* aptr[2];
#pragma unroll
    for (int mi = 0; mi < 2; ++mi)
        aptr[mi] = hin + ((size_t)b * T_ + t0 + wrow * 32 + mi * 16 + l15) * DIN + quad * 8;
    for (int nout = 0; nout < DHID / 128; ++nout) {
        const int nbase = nout * 128;
        f32x4 acc[2][4] = {};
        const unsigned short* bptr[4];
        float b1v[4];
#pragma unroll
        for (int ni = 0; ni < 4; ++ni) {
            int n = nbase + wcol * 64 + ni * 16 + l15;
            bptr[ni] = W1b + (size_t)n * DIN + quad * 8;
            b1v[ni]  = b1[n];
        }
        for (int k = 0; k < DIN; k += 32) {
            BF8 a[2], w[4];
#pragma unroll
            for (int mi = 0; mi < 2; ++mi) {
                float4 f0 = *(const float4*)(aptr[mi] + k);
                float4 f1 = *(const float4*)(aptr[mi] + k + 4);
                a[mi].u[0] = pack2bf(f0.x, f0.y);
                a[mi].u[1] = pack2bf(f0.z, f0.w);
                a[mi].u[2] = pack2bf(f1.x, f1.y);
                a[mi].u[3] = pack2bf(f1.z, f1.w);
            }
#pragma unroll
            for (int ni = 0; ni < 4; ++ni) w[ni].i = *(const i32x4*)(bptr[ni] + k);
#pragma unroll
            for (int mi = 0; mi < 2; ++mi)
#pragma unroll
                for (int ni = 0; ni < 4; ++ni)
                    acc[mi][ni] = __builtin_amdgcn_mfma_f32_16x16x32_bf16(
                        a[mi].v, w[ni].v, acc[mi][ni], 0, 0, 0);
        }
#pragma unroll
        for (int ni = 0; ni < 4; ++ni) {
            float colsum = 0.f;
#pragma unroll
            for (int mi = 0; mi < 2; ++mi) {
                int trow = t0 + wrow * 32 + mi * 16 + quad * 4;
#pragma unroll
                for (int r = 0; r < 4; ++r) {
                    float v = acc[mi][ni][r] + b1v[ni];
                    v = v > 0.f ? v : 0.f;
                    if (trow + r < len) colsum += v;
                }
            }
            colsum += __shfl_xor(colsum, 16);
            colsum += __shfl_xor(colsum, 32);
            if (quad == 0)
                atomicAdd(&pooled[b * DHID + nbase + wcol * 64 + ni * 16 + l15], colsum);
        }
    }
}

// ---- score[b][tag] = pooled[b]·W2[tag] / len + b2[tag] ----
__global__ void finalize_k(const float* __restrict__ pooled,
                           const int*   __restrict__ text_len,
                           const float* __restrict__ W2,
                           const float* __restrict__ b2,
                           float*       __restrict__ out) {
    int b = blockIdx.x, tid = threadIdx.x;
    float s0 = 0.f, s1 = 0.f;
    for (int hh = tid; hh < DHID; hh += 256) {
        float p = pooled[b * DHID + hh];
        s0 += p * W2[hh];
        s1 += p * W2[DHID + hh];
    }
#pragma unroll
    for (int off = 32; off > 0; off >>= 1) {
        s0 += __shfl_down(s0, off);
        s1 += __shfl_down(s1, off);
    }
    __shared__ float r0[4], r1[4];
    int wid = tid >> 6, lane = tid & 63;
    if (lane == 0) { r0[wid] = s0; r1[wid] = s1; }
    __syncthreads();
    if (tid == 0) {
        float inv = 1.0f / (float)text_len[b];
        out[b * 2 + 0] = (r0[0] + r0[1] + r0[2] + r0[3]) * inv + b2[0];
        out[b * 2 + 1] = (r1[0] + r1[1] + r1[2] + r1[3]) * inv + b2[1];
    }
}

extern "C" void kernel_launch(void* const* d_in, const int* in_sizes, int n_in,
                              void* d_out, int out_size, void* d_ws, size_t ws_size,
                              hipStream_t stream) {
    const float* hin      = (const float*)d_in[0];
    const int*   text_len = (const int*)  d_in[1];
    const float* W1       = (const float*)d_in[2];
    const float* b1       = (const float*)d_in[3];
    const float* W2       = (const float*)d_in[4];
    const float* b2       = (const float*)d_in[5];
    float* out = (float*)d_out;

    const size_t HB_BYTES  = (size_t)B_ * T_ * DIN * 2;        // 134 MB
    const size_t W1B_BYTES = (size_t)DHID * DIN * 2;           // 4 MB
    const size_t NEED      = HB_BYTES + W1B_BYTES + (size_t)B_ * DHID * 4;

    if (ws_size >= NEED) {
        unsigned short* hb     = (unsigned short*)d_ws;
        unsigned short* W1b    = (unsigned short*)((char*)d_ws + HB_BYTES);
        float*          pooled = (float*)((char*)d_ws + HB_BYTES + W1B_BYTES);

        convert_w1<<<(DHID * DIN / 4) / 256, 256, 0, stream>>>(W1, W1b, pooled);
        dim3 hgrid((T_ * DIN / 8) / 256, B_);
        convert_h<<<hgrid, 256, 0, stream>>>(hin, text_len, hb);

        dim3 grid(DHID / BN, T_ / BM, B_);
        scorer_gemm_8ph<<<grid, 512, 0, stream>>>(hb, text_len, W1b, b1, pooled);
        finalize_k<<<B_, 256, 0, stream>>>(pooled, text_len, W2, b2, out);
    } else {
        unsigned short* W1b    = (unsigned short*)d_ws;
        float*          pooled = (float*)((char*)d_ws + W1B_BYTES);
        (void)hipMemsetAsync(pooled, 0, B_ * DHID * sizeof(float), stream);
        convert_w1<<<(DHID * DIN / 4) / 256, 256, 0, stream>>>(W1, W1b, pooled);
        dim3 grid(T_ / 64, B_);
        scorer_gemm_direct<<<grid, 256, 0, stream>>>(hin, text_len, W1b, b1, pooled);
        finalize_k<<<B_, 256, 0, stream>>>(pooled, text_len, W2, b2, out);
    }
}

// Round 2
// 508.120 us; speedup vs baseline: 1.1186x; 1.0548x over previous
//
#include <hip/hip_runtime.h>
#include <hip/hip_bf16.h>

#define B_   32
#define T_   2048
#define DIN  1024
#define DHID 2048
#define TAG  2

// ---- GEMM geometry: 256x256x64, 8 waves (2M x 4N), dbuf LDS ----
#define BM   256
#define BN   256
#define BK   64
#define NT   (DIN / BK)          // 16 K-tiles

typedef __attribute__((ext_vector_type(8))) short bf16x8;   // 8 bf16 = 4 VGPRs
typedef __attribute__((ext_vector_type(4))) float f32x4;
typedef __attribute__((ext_vector_type(4))) int   i32x4;

union BF8 { bf16x8 v; i32x4 i; unsigned int u[4]; };

// fp32 -> bf16 round-to-nearest-even, pure integer ops
__device__ inline unsigned int f2bf_u(float f) {
    unsigned int u = __float_as_uint(f);
    return (u + 0x7FFFu + ((u >> 16) & 1u)) >> 16;
}
__device__ inline unsigned int pack2bf(float a, float b) {
    return f2bf_u(a) | (f2bf_u(b) << 16);
}

#define BARRIER()  asm volatile("s_barrier" ::: "memory")
#define LGKM0()    asm volatile("s_waitcnt lgkmcnt(0)" ::: "memory")
#define VMCNT(n)   asm volatile("s_waitcnt vmcnt(" #n ")" ::: "memory")

// ---- W1 fp32 [DHID][DIN] -> bf16 same layout; also zero pooled ----
__global__ void convert_w1(const float* __restrict__ W1,
                           unsigned short* __restrict__ W1b,
                           float* __restrict__ pooled) {
    int idx = blockIdx.x * blockDim.x + threadIdx.x;   // one float4 per thread
    float4 f = ((const float4*)W1)[idx];
    ((uint2*)W1b)[idx] = uint2{pack2bf(f.x, f.y), pack2bf(f.z, f.w)};
    if (idx < B_ * DHID / 4) ((float4*)pooled)[idx] = float4{0.f, 0.f, 0.f, 0.f};
}

// ---- fused conversion: y < B_ -> h rows (bf16, masked rows skipped);
//      y in {B_, B_+1} -> W1 fp32->bf16 (+ pooled zero-init) ----
__global__ void convert_all(const float* __restrict__ h,
                            const int*   __restrict__ text_len,
                            unsigned short* __restrict__ hb,
                            const float* __restrict__ W1,
                            unsigned short* __restrict__ W1b,
                            float* __restrict__ pooled) {
    if (blockIdx.y >= B_) {
        // W1: DHID*DIN/4 = 524288 float4 = 2 y-rows x 1024 blocks x 256 thr
        int idx = ((blockIdx.y - B_) * 1024 + blockIdx.x) * 256 + threadIdx.x;
        float4 f = ((const float4*)W1)[idx];
        ((uint2*)W1b)[idx] = uint2{pack2bf(f.x, f.y), pack2bf(f.z, f.w)};
        if (idx < B_ * DHID / 4) ((float4*)pooled)[idx] = float4{0.f, 0.f, 0.f, 0.f};
        return;
    }
    const int b   = blockIdx.y;
    const int idx = blockIdx.x * 256 + threadIdx.x;       // 0 .. T_*DIN/8-1
    const int t   = idx >> 7;                             // DIN/8 = 128 thr/row
    if (t >= text_len[b]) return;                         // wave-uniform (128 thr/row)
    const size_t gi = (size_t)b * (T_ * DIN / 8) + idx;   // uint4 index
    float4 f0 = ((const float4*)h)[gi * 2];
    float4 f1 = ((const float4*)h)[gi * 2 + 1];
    uint4 o;
    o.x = pack2bf(f0.x, f0.y);
    o.y = pack2bf(f0.z, f0.w);
    o.z = pack2bf(f1.x, f1.y);
    o.w = pack2bf(f1.z, f1.w);
    ((uint4*)hb)[gi] = o;
}

// ---- main GEMM: 256x256 tile, 3 phases/K-tile {12,4,8} ds_reads / {16,16,32}
// MFMA, counted vmcnt(6) once per K-tile, setprio, XOR swizzle, T1 XCD swizzle.
//
// XCD swizzle (1D grid, 2048 blocks): HW round-robins launch-id%8 -> XCD.
//   x = bid&7 (XCD), i = bid>>3, nt = i&7, m = i>>3, tt = m&7, bq = m>>3,
//   b = ((x - tt) & 7) + 8*bq   ->  XCD = (b+tt)%8.
// Properties: (a) the 8 nt-blocks sharing an A-panel are dispatch-adjacent on
// ONE XCD -> A fetched once into that L2; (b) each XCD samples 32 distinct
// (b,tt) cells -> masked-tile raggedness balanced across XCDs; (c) bijective.
//
// Race ledger (same invariant as round 1): a reader's own lgkmcnt(0) gates its
// arrival at the phase-closing barrier; every LDS overwrite is issued >=1
// barrier after the last reader's closing barrier:
//   A-half0(t): read ph0, overwritten ph1 (stage A0(t+2), same buffer)  [1 bar]
//   B-half0(t): read ph0 (regs reused later), overwritten ph2           [2 bar]
//   B-half1(t): read ph1, overwritten ph2 (stage B1(t+2))               [1 bar]
//   A-half1(t): read ph2, overwritten ph0 of t+1 (stage A1(t+2))        [1 bar]
// vmcnt ledger: 8 issues/K-tile; peak 14 outstanding at ph2's VMCNT(6) which
// drains ALL of K-tile t+1 (its 8 loads are the oldest) leaving {A0,B0,B1}(t+2).
__global__ __launch_bounds__(512, 2) void scorer_gemm_8ph(
    const unsigned short* __restrict__ hb,    // [B,T,DIN] bf16
    const int*            __restrict__ text_len,
    const unsigned short* __restrict__ W1b,   // [DHID,DIN] bf16
    const float*          __restrict__ b1,
    float*                __restrict__ pooled) {

    // ---- T1 XCD-aware de-swizzle ----
    const int bid = blockIdx.x;
    const int x   = bid & 7;
    const int i   = bid >> 3;
    const int nt  = i & 7;
    const int m   = i >> 3;
    const int tt  = m & 7;
    const int bq  = m >> 3;
    const int b   = ((x - tt) & 7) + (bq << 3);

    const int len = text_len[b];
    const int t0  = tt * BM;
    if (t0 >= len) return;                    // fully masked tile (block-uniform)
    const int n0  = nt * BN;

    __shared__ __align__(16) unsigned short lds[4 * BM * BK];  // 128 KB: A0 A1 B0 B1

    const int tid  = threadIdx.x;
    const int lane = tid & 63;
    const int wid  = tid >> 6;       // 0..7
    const int wm   = wid >> 2;       // 0..1  (M wave)
    const int wn   = wid & 3;        // 0..3  (N wave)
    const int quad = lane >> 4;
    const int l15  = lane & 15;

    // staging: per global_load_lds issue, 512 threads cover 64 rows (8 rows/wave,
    // 8 x 16B chunks/row). LDS dest is wave-uniform; HW adds lane*16.
    const int srow   = lane >> 3;                 // 0..7 row within wave's 8-row group
    const int schunk = (lane & 7) ^ srow;         // pre-swizzled source chunk
    const unsigned short* gA = hb  + ((size_t)b * T_ + t0 + wid * 8 + srow) * DIN + schunk * 8;
    const unsigned short* gB = W1b + ((size_t)(n0 + wid * 8 + srow)) * DIN + schunk * 8;
    const int sdst = wid * 512;                   // shorts, wave-uniform

    auto stageA = [&](int d, int h, int k0) {
#pragma unroll
        for (int j = 0; j < 2; ++j) {
            const unsigned short* gp = gA + (size_t)(h * 128 + j * 64) * DIN + k0;
            __builtin_amdgcn_global_load_lds(
                (const __attribute__((address_space(1))) void*)gp,
                (__attribute__((address_space(3))) void*)(lds + d * 16384 + (h * 128 + j * 64) * 64 + sdst),
                16, 0, 0);
        }
    };
    auto stageB = [&](int d, int h, int k0) {
#pragma unroll
        for (int j = 0; j < 2; ++j) {
            const unsigned short* gp = gB + (size_t)(h * 128 + j * 64) * DIN + k0;
            __builtin_amdgcn_global_load_lds(
                (const __attribute__((address_space(1))) void*)gp,
                (__attribute__((address_space(3))) void*)(lds + 32768 + d * 16384 + (h * 128 + j * 64) * 64 + sdst),
                16, 0, 0);
        }
    };

    // fragment rows: mi 0..7 -> row (mi>>2)*128 + wm*64 + (mi&3)*16  (mi<4 = half0)
    //                ni 0..3 -> row (ni>>1)*128 + wn*32 + (ni&1)*16  (ni<2 = half0)
    auto rdA = [&](const unsigned short* As, int mi, int ks) -> i32x4 {
        int row  = (mi >> 2) * 128 + wm * 64 + (mi & 3) * 16 + l15;
        int slot = (ks * 4 + quad) ^ (l15 & 7);
        return *(const i32x4*)(As + row * 64 + slot * 8);
    };
    auto rdB = [&](const unsigned short* Bs, int ni, int ks) -> i32x4 {
        int row  = (ni >> 1) * 128 + wn * 32 + (ni & 1) * 16 + l15;
        int slot = (ks * 4 + quad) ^ (l15 & 7);
        return *(const i32x4*)(Bs + row * 64 + slot * 8);
    };

    f32x4 acc[8][4] = {};
    BF8 a[4][2], bb[4][2];

    // ---- prologue: K-tile 0 complete + 3 half-tiles of K-tile 1 in flight ----
    stageA(0, 0, 0);  stageB(0, 0, 0);  stageB(0, 1, 0);  stageA(0, 1, 0);
    stageA(1, 0, BK); stageB(1, 0, BK); stageB(1, 1, BK);
    VMCNT(6);                      // oldest 8 loads (= all of K-tile 0) landed
    BARRIER();

    for (int t = 0; t < NT; ++t) {
        const int k0 = t * BK;
        const unsigned short* As = lds + (t & 1) * 16384;
        const unsigned short* Bs = lds + 32768 + (t & 1) * 16384;

        // ---- phase 0: read A-half0 (8) + B-half0 (4); stage A-half1(t+1); Q00
#pragma unroll
        for (int mi = 0; mi < 4; ++mi)
#pragma unroll
            for (int ks = 0; ks < 2; ++ks)
                a[mi][ks].i = rdA(As, mi, ks);
#pragma unroll
        for (int ni = 0; ni < 2; ++ni)
#pragma unroll
            for (int ks = 0; ks < 2; ++ks)
                bb[ni][ks].i = rdB(Bs, ni, ks);
        if (t + 1 < NT) stageA((t + 1) & 1, 1, k0 + BK);
        BARRIER();
        LGKM0();
        __builtin_amdgcn_s_setprio(1);
#pragma unroll
        for (int mi = 0; mi < 4; ++mi)
#pragma unroll
            for (int ni = 0; ni < 2; ++ni)
#pragma unroll
                for (int ks = 0; ks < 2; ++ks)
                    acc[mi][ni] = __builtin_amdgcn_mfma_f32_16x16x32_bf16(
                        a[mi][ks].v, bb[ni][ks].v, acc[mi][ni], 0, 0, 0);
        __builtin_amdgcn_s_setprio(0);
        BARRIER();

        // ---- phase 1: read B-half1 (4); stage A-half0(t+2); Q01
#pragma unroll
        for (int ni = 2; ni < 4; ++ni)
#pragma unroll
            for (int ks = 0; ks < 2; ++ks)
                bb[ni][ks].i = rdB(Bs, ni, ks);
        if (t + 2 < NT) stageA(t & 1, 0, k0 + 2 * BK);
        BARRIER();
        LGKM0();
        __builtin_amdgcn_s_setprio(1);
#pragma unroll
        for (int mi = 0; mi < 4; ++mi)
#pragma unroll
            for (int ni = 2; ni < 4; ++ni)
#pragma unroll
                for (int ks = 0; ks < 2; ++ks)
                    acc[mi][ni] = __builtin_amdgcn_mfma_f32_16x16x32_bf16(
                        a[mi][ks].v, bb[ni][ks].v, acc[mi][ni], 0, 0, 0);
        __builtin_amdgcn_s_setprio(0);
        BARRIER();

        // ---- phase 2 (merged): read A-half1 (8); stage B-half0+1(t+2); vmcnt;
        //      Q10 + Q11 (32 MFMA)
#pragma unroll
        for (int mi = 0; mi < 4; ++mi)
#pragma unroll
            for (int ks = 0; ks < 2; ++ks)
                a[mi][ks].i = rdA(As, mi + 4, ks);
        if (t + 2 < NT) {
            stageB(t & 1, 0, k0 + 2 * BK);
            stageB(t & 1, 1, k0 + 2 * BK);
        }
        if (t < NT - 2)       { VMCNT(6); }   // steady: 3 half-tiles stay in flight
        else if (t == NT - 2) { VMCNT(0); }   // tail: drain last prefetch
        BARRIER();
        LGKM0();
        __builtin_amdgcn_s_setprio(1);
#pragma unroll
        for (int mi = 0; mi < 4; ++mi)
#pragma unroll
            for (int ni = 0; ni < 4; ++ni)
#pragma unroll
                for (int ks = 0; ks < 2; ++ks)
                    acc[4 + mi][ni] = __builtin_amdgcn_mfma_f32_16x16x32_bf16(
                        a[mi][ks].v, bb[ni][ks].v, acc[4 + mi][ni], 0, 0, 0);
        __builtin_amdgcn_s_setprio(0);
        BARRIER();
    }

    // ---- epilogue: +b1, relu, mask, reduce over m (regs then quad-shfl), atomicAdd
    // C/D layout: col = lane&15 (n), row = quad*4 + reg (m)
#pragma unroll
    for (int ni = 0; ni < 4; ++ni) {
        int n = n0 + (ni >> 1) * 128 + wn * 32 + (ni & 1) * 16 + l15;
        float bias = b1[n];
        float colsum = 0.f;
#pragma unroll
        for (int mi = 0; mi < 8; ++mi) {
            int trow = t0 + (mi >> 2) * 128 + wm * 64 + (mi & 3) * 16 + quad * 4;
#pragma unroll
            for (int r = 0; r < 4; ++r) {
                float v = acc[mi][ni][r] + bias;
                v = v > 0.f ? v : 0.f;
                if (trow + r < len) colsum += v;
            }
        }
        colsum += __shfl_xor(colsum, 16);
        colsum += __shfl_xor(colsum, 32);
        if (quad == 0) atomicAdd(&pooled[b * DHID + n], colsum);
    }
}

// ---- fallback (no hb workspace) ----
__global__ void scorer_gemm_direct(const float* __restrict__ hin,
                                   const int*   __restrict__ text_len,
                                   const unsigned short* __restrict__ W1b,
                                   const float* __restrict__ b1,
                                   float*       __restrict__ pooled) {
    const int tt  = blockIdx.x;
    const int b   = blockIdx.y;
    const int len = text_len[b];
    const int t0  = tt * 64;
    if (t0 >= len) return;
    const int tid = threadIdx.x, lane = tid & 63, wid = tid >> 6;
    const int wrow = wid >> 1, wcol = wid & 1, quad = lane >> 4, l15 = lane & 15;
    const float* aptr[2];
#pragma unroll
    for (int mi = 0; mi < 2; ++mi)
        aptr[mi] = hin + ((size_t)b * T_ + t0 + wrow * 32 + mi * 16 + l15) * DIN + quad * 8;
    for (int nout = 0; nout < DHID / 128; ++nout) {
        const int nbase = nout * 128;
        f32x4 acc[2][4] = {};
        const unsigned short* bptr[4];
        float b1v[4];
#pragma unroll
        for (int ni = 0; ni < 4; ++ni) {
            int n = nbase + wcol * 64 + ni * 16 + l15;
            bptr[ni] = W1b + (size_t)n * DIN + quad * 8;
            b1v[ni]  = b1[n];
        }
        for (int k = 0; k < DIN; k += 32) {
            BF8 a[2], w[4];
#pragma unroll
            for (int mi = 0; mi < 2; ++mi) {
                float4 f0 = *(const float4*)(aptr[mi] + k);
                float4 f1 = *(const float4*)(aptr[mi] + k + 4);
                a[mi].u[0] = pack2bf(f0.x, f0.y);
                a[mi].u[1] = pack2bf(f0.z, f0.w);
                a[mi].u[2] = pack2bf(f1.x, f1.y);
                a[mi].u[3] = pack2bf(f1.z, f1.w);
            }
#pragma unroll
            for (int ni = 0; ni < 4; ++ni) w[ni].i = *(const i32x4*)(bptr[ni] + k);
#pragma unroll
            for (int mi = 0; mi < 2; ++mi)
#pragma unroll
                for (int ni = 0; ni < 4; ++ni)
                    acc[mi][ni] = __builtin_amdgcn_mfma_f32_16x16x32_bf16(
                        a[mi].v, w[ni].v, acc[mi][ni], 0, 0, 0);
        }
#pragma unroll
        for (int ni = 0; ni < 4; ++ni) {
            float colsum = 0.f;
#pragma unroll
            for (int mi = 0; mi < 2; ++mi) {
                int trow = t0 + wrow * 32 + mi * 16 + quad * 4;
#pragma unroll
                for (int r = 0; r < 4; ++r) {
                    float v = acc[mi][ni][r] + b1v[ni];
                    v = v > 0.f ? v : 0.f;
                    if (trow + r < len) colsum += v;
                }
            }
            colsum += __shfl_xor(colsum, 16);
            colsum += __shfl_xor(colsum, 32);
            if (quad == 0)
                atomicAdd(&pooled[b * DHID + nbase + wcol * 64 + ni * 16 + l15], colsum);
        }
    }
}

// ---- score[b][tag] = pooled[b]·W2[tag] / len + b2[tag] ----
__global__ void finalize_k(const float* __restrict__ pooled,
                           const int*   __restrict__ text_len,
                           const float* __restrict__ W2,
                           const float* __restrict__ b2,
                           float*       __restrict__ out) {
    int b = blockIdx.x, tid = threadIdx.x;
    float s0 = 0.f, s1 = 0.f;
    for (int hh = tid; hh < DHID; hh += 256) {
        float p = pooled[b * DHID + hh];
        s0 += p * W2[hh];
        s1 += p * W2[DHID + hh];
    }
#pragma unroll
    for (int off = 32; off > 0; off >>= 1) {
        s0 += __shfl_down(s0, off);
        s1 += __shfl_down(s1, off);
    }
    __shared__ float r0[4], r1[4];
    int wid = tid >> 6, lane = tid & 63;
    if (lane == 0) { r0[wid] = s0; r1[wid] = s1; }
    __syncthreads();
    if (tid == 0) {
        float inv = 1.0f / (float)text_len[b];
        out[b * 2 + 0] = (r0[0] + r0[1] + r0[2] + r0[3]) * inv + b2[0];
        out[b * 2 + 1] = (r1[0] + r1[1] + r1[2] + r1[3]) * inv + b2[1];
    }
}

extern "C" void kernel_launch(void* const* d_in, const int* in_sizes, int n_in,
                              void* d_out, int out_size, void* d_ws, size_t ws_size,
                              hipStream_t stream) {
    const float* hin      = (const float*)d_in[0];
    const int*   text_len = (const int*)  d_in[1];
    const float* W1       = (const float*)d_in[2];
    const float* b1       = (const float*)d_in[3];
    const float* W2       = (const float*)d_in[4];
    const float* b2       = (const float*)d_in[5];
    float* out = (float*)d_out;

    const size_t HB_BYTES  = (size_t)B_ * T_ * DIN * 2;        // 134 MB
    const size_t W1B_BYTES = (size_t)DHID * DIN * 2;           // 4 MB
    const size_t NEED      = HB_BYTES + W1B_BYTES + (size_t)B_ * DHID * 4;

    if (ws_size >= NEED) {
        unsigned short* hb     = (unsigned short*)d_ws;
        unsigned short* W1b    = (unsigned short*)((char*)d_ws + HB_BYTES);
        float*          pooled = (float*)((char*)d_ws + HB_BYTES + W1B_BYTES);

        dim3 cgrid(1024, B_ + 2);     // y<B_: h rows; y>=B_: W1 (+pooled zero)
        convert_all<<<cgrid, 256, 0, stream>>>(hin, text_len, hb, W1, W1b, pooled);

        scorer_gemm_8ph<<<2048, 512, 0, stream>>>(hb, text_len, W1b, b1, pooled);
        finalize_k<<<B_, 256, 0, stream>>>(pooled, text_len, W2, b2, out);
    } else {
        unsigned short* W1b    = (unsigned short*)d_ws;
        float*          pooled = (float*)((char*)d_ws + W1B_BYTES);
        (void)hipMemsetAsync(pooled, 0, B_ * DHID * sizeof(float), stream);
        convert_w1<<<(DHID * DIN / 4) / 256, 256, 0, stream>>>(W1, W1b, pooled);
        dim3 grid(T_ / 64, B_);
        scorer_gemm_direct<<<grid, 256, 0, stream>>>(hin, text_len, W1b, b1, pooled);
        finalize_k<<<B_, 256, 0, stream>>>(pooled, text_len, W2, b2, out);
    }
}